// Round 2
// baseline (1115.828 us; speedup 1.0000x reference)
//
#include <hip/hip_runtime.h>

// PolicyHead fused kernel, R4.
// R3 post-mortem: __launch_bounds__(256,4) forced VGPR=64 -> ~320 MB of
// scratch-spill stores (WRITE_SIZE 30->349 MB) + reloads. Occupancy gain
// (46%) was real but spill latency ate most of it.
// R4 changes:
//  - __launch_bounds__(256) only. LDS (33 KB) caps us at 4 blocks/CU anyway;
//    VGPR ~116 <= 128 keeps 4 waves/EU WITHOUT spills (R2 evidence: VGPR=116,
//    WRITE_SIZE == output size exactly).
//  - Bias folded into MFMA C-operand init (removes 64 v_add per layer).
//  - Promo dot-product vectorized: 4x ds_read_b128 per lane instead of 32x
//    ds_read_u16.
//  - Logits loop gets dual accumulators too (same ILP trick as layers).

typedef __bf16 bf16_t;
typedef __bf16 bf16x8 __attribute__((ext_vector_type(8)));
typedef float  f32x4  __attribute__((ext_vector_type(4)));

#define PSCALE 0.0625f
#define NPOL   1858

__global__ void prep_weights(const float* __restrict__ w1,
                             const float* __restrict__ w2,
                             const float* __restrict__ w3,
                             bf16_t* __restrict__ wf) {
    // wf flat layout: [which][n(16)][t(8)][lane(64)][j(8)]
    int i = blockIdx.x * 256 + threadIdx.x;      // 0 .. 3*65536-1
    int which = i >> 16;
    int r = i & 65535;
    int j    = r & 7;
    int lane = (r >> 3) & 63;
    int t    = (r >> 9) & 7;
    int n    = (r >> 12) & 15;
    const float* w = (which == 0) ? w1 : (which == 1 ? w2 : w3);
    int row = n * 16 + (lane & 15);              // output-col index (w row)
    int col = t * 32 + (lane >> 4) * 8 + j;      // k index
    wf[i] = (bf16_t)w[row * 256 + col];
}

// B-operand fragment for col-tile n, k-tile t: lane holds
// w[n*16 + (lane&15)][t*32 + (lane>>4)*8 + j], j=0..7.
template <bool USE_WS>
__device__ __forceinline__ bf16x8 wfrag(const bf16_t* __restrict__ wl,
                                        const float* __restrict__ w,
                                        int n, int t, int lane) {
    if (USE_WS) {
        return *(const bf16x8*)(wl + (((n * 8 + t) * 64 + lane) << 3));
    } else {
        int l15 = lane & 15, quad = lane >> 4;
        const float* p = w + (n * 16 + l15) * 256 + t * 32 + quad * 8;
        f32x4 lo = *(const f32x4*)p;
        f32x4 hi = *(const f32x4*)(p + 4);
        bf16x8 v;
        v[0] = (bf16_t)lo[0]; v[1] = (bf16_t)lo[1];
        v[2] = (bf16_t)lo[2]; v[3] = (bf16_t)lo[3];
        v[4] = (bf16_t)hi[0]; v[5] = (bf16_t)hi[1];
        v[6] = (bf16_t)hi[2]; v[7] = (bf16_t)hi[3];
        return v;
    }
}

// Swizzled byte offset into the 64x256 bf16 union buffer.
// b128 reads at col%8==0 stay 16B-aligned (XOR touches bits 4..6 only).
__device__ __forceinline__ int ks_off(int row, int col) {
    return ((row << 9) + (col << 1)) ^ ((row & 7) << 4);
}

// 16-row x 16-col output tile of in[16x256] @ w[256x256].T, bias pre-loaded
// into the even accumulator (C/D layout: col = lane&15, all 4 rows same col).
template <bool USE_WS>
__device__ __forceinline__ f32x4 gemm_row16(const bf16x8* in,
                                            const bf16_t* __restrict__ wl,
                                            const float* __restrict__ wraw,
                                            int n, int lane, float bias) {
    f32x4 a0 = {bias, bias, bias, bias};
    f32x4 a1 = {0.f, 0.f, 0.f, 0.f};
    #pragma unroll
    for (int t = 0; t < 8; t += 2) {
        a0 = __builtin_amdgcn_mfma_f32_16x16x32_bf16(
                 in[t],     wfrag<USE_WS>(wl, wraw, n, t,     lane), a0, 0, 0, 0);
        a1 = __builtin_amdgcn_mfma_f32_16x16x32_bf16(
                 in[t + 1], wfrag<USE_WS>(wl, wraw, n, t + 1, lane), a1, 0, 0, 0);
    }
    return a0 + a1;
}

template <bool USE_WS>
__global__ __launch_bounds__(256)
void policy_main(const float* __restrict__ x,
                 const bf16_t* __restrict__ wf,   // [3][16][8][64][8] bf16
                 const float* __restrict__ w1,
                 const float* __restrict__ w2,
                 const float* __restrict__ w3,
                 const float* __restrict__ b1,
                 const float* __restrict__ b2,
                 const float* __restrict__ b3,
                 const float* __restrict__ w4,
                 const int*   __restrict__ gidx,
                 float* __restrict__ out) {
    // 32768 B union: phase A = k (64 rows x 256 bf16, XOR-swizzled);
    //                phase B = fullbuf (67x64 f32 = 17152 B, linear).
    __shared__ __align__(16) unsigned char u_lds[64 * 512];
    __shared__ float promoLDS[4][8];
    __shared__ float patchLDS[8][8];   // logits[48:56, 56:64], scaled

    const int tid  = threadIdx.x;
    const int lane = tid & 63;
    const int wv   = tid >> 6;        // wave id 0..3
    const int quad = lane >> 4;       // 0..3
    const int l15  = lane & 15;
    const int bat  = blockIdx.x;
    const int R    = wv * 16;         // row base within batch

    // ---- x A-fragments (fp32 -> bf16). xa[t][j] = x[R+l15][t*32+quad*8+j]
    bf16x8 xa[8];
    {
        const float* xrow = x + ((size_t)bat * 64 + R + l15) * 256;
        #pragma unroll
        for (int t = 0; t < 8; ++t) {
            f32x4 lo = *(const f32x4*)(xrow + t * 32 + quad * 8);
            f32x4 hi = *(const f32x4*)(xrow + t * 32 + quad * 8 + 4);
            bf16x8 v;
            v[0] = (bf16_t)lo[0]; v[1] = (bf16_t)lo[1];
            v[2] = (bf16_t)lo[2]; v[3] = (bf16_t)lo[3];
            v[4] = (bf16_t)hi[0]; v[5] = (bf16_t)hi[1];
            v[6] = (bf16_t)hi[2]; v[7] = (bf16_t)hi[3];
            xa[t] = v;
        }
    }

    bf16x8 oa[8];   // out A-frags (layer-2/3 input)
    bf16x8 qa[8];   // q  A-frags (logits input)

    // ---------------- layer 1: out = relu(x@w1.T + b1) -> oa ----------------
    // Bulk transpose through the wave's 16-row slice of the swizzled buffer.
    {
        const bf16_t* wl = wf;
        #pragma unroll
        for (int n = 0; n < 16; ++n) {
            f32x4 acc = gemm_row16<USE_WS>(xa, wl, w1, n, lane, b1[n * 16 + l15]);
            #pragma unroll
            for (int r2 = 0; r2 < 4; ++r2) {
                float v = fmaxf(acc[r2], 0.f);
                *(bf16_t*)(u_lds + ks_off(R + quad * 4 + r2, n * 16 + l15)) = (bf16_t)v;
            }
        }
        #pragma unroll
        for (int t = 0; t < 8; ++t)
            oa[t] = *(const bf16x8*)(u_lds + ks_off(R + l15, t * 32 + quad * 8));
    }

    // ---------------- layer 2: q = out@w2.T + b2 -> qa ----------------
    {
        const bf16_t* wl = wf + 65536;
        #pragma unroll
        for (int n = 0; n < 16; ++n) {
            f32x4 acc = gemm_row16<USE_WS>(oa, wl, w2, n, lane, b2[n * 16 + l15]);
            #pragma unroll
            for (int r2 = 0; r2 < 4; ++r2)
                *(bf16_t*)(u_lds + ks_off(R + quad * 4 + r2, n * 16 + l15)) =
                    (bf16_t)acc[r2];
        }
        #pragma unroll
        for (int t = 0; t < 8; ++t)
            qa[t] = *(const bf16x8*)(u_lds + ks_off(R + l15, t * 32 + quad * 8));
    }

    // ---------------- layer 3: k = out@w3.T + b3 -> ks (LDS) ----------------
    {
        const bf16_t* wl = wf + 2 * 65536;
        #pragma unroll
        for (int n = 0; n < 16; ++n) {
            f32x4 acc = gemm_row16<USE_WS>(oa, wl, w3, n, lane, b3[n * 16 + l15]);
            #pragma unroll
            for (int r2 = 0; r2 < 4; ++r2)
                *(bf16_t*)(u_lds + ks_off(R + quad * 4 + r2, n * 16 + l15)) =
                    (bf16_t)acc[r2];
        }
    }

    __syncthreads();   // #1: ks complete across all waves

    // ---------------- logits = q@k.T * SCALE -> registers -------------------
    f32x4 la[4];
    {
        #pragma unroll
        for (int n = 0; n < 4; ++n) {
            f32x4 a0 = {0.f, 0.f, 0.f, 0.f};
            f32x4 a1 = {0.f, 0.f, 0.f, 0.f};
            #pragma unroll
            for (int t = 0; t < 8; t += 2) {
                bf16x8 k0 = *(const bf16x8*)(u_lds + ks_off(n * 16 + l15,
                                                            t * 32 + quad * 8));
                bf16x8 k1 = *(const bf16x8*)(u_lds + ks_off(n * 16 + l15,
                                                            (t + 1) * 32 + quad * 8));
                a0 = __builtin_amdgcn_mfma_f32_16x16x32_bf16(qa[t],     k0, a0, 0, 0, 0);
                a1 = __builtin_amdgcn_mfma_f32_16x16x32_bf16(qa[t + 1], k1, a1, 0, 0, 0);
            }
            la[n] = a0 + a1;
        }
    }

    // ---------------- promo offsets: offs[p][s] = k[56+s]·w4[p] -------------
    {
        int s = lane >> 3, seg = lane & 7;     // wave wv handles p = wv
        const float* wrow = w4 + wv * 256;
        float p = 0.f;
        #pragma unroll
        for (int m = 0; m < 4; ++m) {
            bf16x8 kv = *(const bf16x8*)(u_lds + ks_off(56 + s, seg * 32 + m * 8));
            f32x4 wa = *(const f32x4*)(wrow + seg * 32 + m * 8);
            f32x4 wb = *(const f32x4*)(wrow + seg * 32 + m * 8 + 4);
            p += (float)kv[0] * wa[0] + (float)kv[1] * wa[1]
               + (float)kv[2] * wa[2] + (float)kv[3] * wa[3]
               + (float)kv[4] * wb[0] + (float)kv[5] * wb[1]
               + (float)kv[6] * wb[2] + (float)kv[7] * wb[3];
        }
        p += __shfl_down(p, 4);
        p += __shfl_down(p, 2);
        p += __shfl_down(p, 1);
        if (seg == 0) promoLDS[wv][s] = p;
    }

    // wave 3 stages the logits[48:56, 56:64] patch (rows 48-55 = quads 0,1)
    if (wv == 3 && quad < 2 && l15 >= 8) {
        #pragma unroll
        for (int r2 = 0; r2 < 4; ++r2)
            patchLDS[quad * 4 + r2][l15 - 8] = la[3][r2] * PSCALE;
    }

    __syncthreads();   // #2: everyone done READING ks; promoLDS/patch ready

    // ---------------- fullbuf (aliased over ks region) ----------------------
    float* fullbuf = (float*)u_lds;
    #pragma unroll
    for (int n = 0; n < 4; ++n) {
        #pragma unroll
        for (int r2 = 0; r2 < 4; ++r2)
            fullbuf[(R + quad * 4 + r2) * 64 + n * 16 + l15] = la[n][r2] * PSCALE;
    }

    // promo rows 64..66 (reads patchLDS/promoLDS only, no fullbuf dependency)
    if (tid < 192) {
        int u = tid >> 6, vv = tid & 63;
        int mm = u * 64 + vv;                  // flat 0..191 over (8 x 24)
        int r_ = mm / 24, c_ = mm - r_ * 24;
        int c3 = c_ / 3, cp = c_ - c3 * 3;     // c3 = s (0..7), cp = p (0..2)
        fullbuf[(64 + u) * 64 + vv] =
            promoLDS[cp][c3] + promoLDS[3][c3] + patchLDS[r_][c3];
    }

    __syncthreads();   // #3: fullbuf ready

    // ---------------- gather (batched: loads, then LDS reads, then stores) --
    {
        float* orow = out + (size_t)bat * NPOL;
        int   idxv[8];
        float valv[8];
        #pragma unroll
        for (int i = 0; i < 8; ++i) {
            int g = tid + i * 256;
            idxv[i] = (g < NPOL) ? gidx[g] : 0;
        }
        #pragma unroll
        for (int i = 0; i < 8; ++i)
            valv[i] = fullbuf[idxv[i]];
        #pragma unroll
        for (int i = 0; i < 8; ++i) {
            int g = tid + i * 256;
            if (g < NPOL) orow[g] = valv[i];
        }
    }
}

extern "C" void kernel_launch(void* const* d_in, const int* in_sizes, int n_in,
                              void* d_out, int out_size, void* d_ws, size_t ws_size,
                              hipStream_t stream) {
    const float* x    = (const float*)d_in[0];
    const float* w1   = (const float*)d_in[1];
    const float* b1   = (const float*)d_in[2];
    const float* w2   = (const float*)d_in[3];
    const float* b2   = (const float*)d_in[4];
    const float* w3   = (const float*)d_in[5];
    const float* b3   = (const float*)d_in[6];
    const float* w4   = (const float*)d_in[7];
    const int*   gidx = (const int*)d_in[8];
    float* out = (float*)d_out;
    bf16_t* wf = (bf16_t*)d_ws;                 // needs 3*65536 bf16 = 384 KB

    int nbat = in_sizes[0] / (64 * 256);        // 4096
    const size_t ws_needed = (size_t)3 * 65536 * sizeof(bf16_t);

    if (ws_size >= ws_needed) {
        prep_weights<<<768, 256, 0, stream>>>(w1, w2, w3, wf);
        policy_main<true><<<nbat, 256, 0, stream>>>(
            x, wf, w1, w2, w3, b1, b2, b3, w4, gidx, out);
    } else {
        policy_main<false><<<nbat, 256, 0, stream>>>(
            x, wf, w1, w2, w3, b1, b2, b3, w4, gidx, out);
    }
}

// Round 3
// 589.451 us; speedup vs baseline: 1.8930x; 1.8930x over previous
//
#include <hip/hip_runtime.h>

// PolicyHead fused kernel, R5.
// R4 post-mortem: time is ∝ 1/resident-streams (R3 46% occ / 472us vs R4 24%
// occ / 871us, ratio match). VGPR=108 arch still lands at 2 waves/SIMD: the
// unified-file footprint (arch+acc, rounded) exceeds the 128 cliff, and
// forcing below it (R3) costs ~320 MB of spill traffic.
// R5: keep 2 waves/SIMD but process TWO batches per block, interleaved:
//  - streams/CU = 8 waves x 2 = 16 (R3 level) with ZERO spills
//  - each weight fragment load feeds 2 MFMAs (half the wfrag loads)
//  - 4 accumulator chains -> 4x MFMA ILP
//  - gidx gather loads shared across the 2 batches
//  - bias back in the epilogue (R4 put it in the MFMA C-init: bias load
//    serialized ahead of the whole chain)
// LDS = 2x32KB k-buffers (XOR swizzle) + small = 66.3 KB -> 2 blocks/CU.
// __launch_bounds__(256,2): cap 256 VGPR (peak live ~190).

typedef __bf16 bf16_t;
typedef __bf16 bf16x8 __attribute__((ext_vector_type(8)));
typedef float  f32x4  __attribute__((ext_vector_type(4)));

#define PSCALE 0.0625f
#define NPOL   1858

__global__ void prep_weights(const float* __restrict__ w1,
                             const float* __restrict__ w2,
                             const float* __restrict__ w3,
                             bf16_t* __restrict__ wf) {
    // wf flat layout: [which][n(16)][t(8)][lane(64)][j(8)]
    int i = blockIdx.x * 256 + threadIdx.x;      // 0 .. 3*65536-1
    int which = i >> 16;
    int r = i & 65535;
    int j    = r & 7;
    int lane = (r >> 3) & 63;
    int t    = (r >> 9) & 7;
    int n    = (r >> 12) & 15;
    const float* w = (which == 0) ? w1 : (which == 1 ? w2 : w3);
    int row = n * 16 + (lane & 15);              // output-col index (w row)
    int col = t * 32 + (lane >> 4) * 8 + j;      // k index
    wf[i] = (bf16_t)w[row * 256 + col];
}

// B-operand fragment for col-tile n, k-tile t: lane holds
// w[n*16 + (lane&15)][t*32 + (lane>>4)*8 + j], j=0..7.
template <bool USE_WS>
__device__ __forceinline__ bf16x8 wfrag(const bf16_t* __restrict__ wl,
                                        const float* __restrict__ w,
                                        int n, int t, int lane) {
    if (USE_WS) {
        return *(const bf16x8*)(wl + (((n * 8 + t) * 64 + lane) << 3));
    } else {
        int l15 = lane & 15, quad = lane >> 4;
        const float* p = w + (n * 16 + l15) * 256 + t * 32 + quad * 8;
        f32x4 lo = *(const f32x4*)p;
        f32x4 hi = *(const f32x4*)(p + 4);
        bf16x8 v;
        v[0] = (bf16_t)lo[0]; v[1] = (bf16_t)lo[1];
        v[2] = (bf16_t)lo[2]; v[3] = (bf16_t)lo[3];
        v[4] = (bf16_t)hi[0]; v[5] = (bf16_t)hi[1];
        v[6] = (bf16_t)hi[2]; v[7] = (bf16_t)hi[3];
        return v;
    }
}

// Swizzled byte offset into a 64x256 bf16 buffer (32768 B).
// b128 reads at col%8==0 stay 16B-aligned (XOR touches bits 4..6 only).
__device__ __forceinline__ int ks_off(int row, int col) {
    return ((row << 9) + (col << 1)) ^ ((row & 7) << 4);
}

__device__ __forceinline__ bf16x8 cvt8(const float* __restrict__ p) {
    f32x4 lo = *(const f32x4*)p;
    f32x4 hi = *(const f32x4*)(p + 4);
    bf16x8 v;
    v[0] = (bf16_t)lo[0]; v[1] = (bf16_t)lo[1];
    v[2] = (bf16_t)lo[2]; v[3] = (bf16_t)lo[3];
    v[4] = (bf16_t)hi[0]; v[5] = (bf16_t)hi[1];
    v[6] = (bf16_t)hi[2]; v[7] = (bf16_t)hi[3];
    return v;
}

// Two-batch 16x16 output tile: shared weight fragments, 4 acc chains.
template <bool USE_WS>
__device__ __forceinline__ void gemm2(const bf16x8* inA, const bf16x8* inB,
                                      const bf16_t* __restrict__ wl,
                                      const float* __restrict__ wraw,
                                      int n, int lane, f32x4& o0, f32x4& o1) {
    f32x4 a00 = {0.f,0.f,0.f,0.f}, a01 = {0.f,0.f,0.f,0.f};
    f32x4 a10 = {0.f,0.f,0.f,0.f}, a11 = {0.f,0.f,0.f,0.f};
    #pragma unroll
    for (int t = 0; t < 8; t += 2) {
        bf16x8 w0 = wfrag<USE_WS>(wl, wraw, n, t,     lane);
        bf16x8 w1 = wfrag<USE_WS>(wl, wraw, n, t + 1, lane);
        a00 = __builtin_amdgcn_mfma_f32_16x16x32_bf16(inA[t],     w0, a00, 0, 0, 0);
        a10 = __builtin_amdgcn_mfma_f32_16x16x32_bf16(inB[t],     w0, a10, 0, 0, 0);
        a01 = __builtin_amdgcn_mfma_f32_16x16x32_bf16(inA[t + 1], w1, a01, 0, 0, 0);
        a11 = __builtin_amdgcn_mfma_f32_16x16x32_bf16(inB[t + 1], w1, a11, 0, 0, 0);
    }
    o0 = a00 + a01;
    o1 = a10 + a11;
}

template <bool USE_WS>
__global__ __launch_bounds__(256, 2)
void policy_main(const float* __restrict__ x,
                 const bf16_t* __restrict__ wf,   // [3][16][8][64][8] bf16
                 const float* __restrict__ w1,
                 const float* __restrict__ w2,
                 const float* __restrict__ w3,
                 const float* __restrict__ b1,
                 const float* __restrict__ b2,
                 const float* __restrict__ b3,
                 const float* __restrict__ w4,
                 const int*   __restrict__ gidx,
                 float* __restrict__ out,
                 int nbat) {
    // Two 32768 B unions: phase A = k (64x256 bf16, XOR-swizzled) per batch;
    //                     phase B = fullbuf (67x64 f32 = 17152 B) per batch.
    __shared__ __align__(16) unsigned char u_lds[2 * 32768];
    __shared__ float promoLDS[2][4][8];
    __shared__ float patchLDS[2][8][8];  // logits[48:56, 56:64], scaled

    const int tid  = threadIdx.x;
    const int lane = tid & 63;
    const int wv   = tid >> 6;        // wave id 0..3
    const int quad = lane >> 4;       // 0..3
    const int l15  = lane & 15;
    const int R    = wv * 16;         // row base within batch

    const int bat0 = blockIdx.x * 2;
    const bool has1 = (bat0 + 1) < nbat;
    const int bat1 = has1 ? bat0 + 1 : bat0;   // clamp: compute dup, skip store

    // ---- x A-fragments (fp32 -> bf16), both batches ----
    bf16x8 xa0[8], xa1[8];
    {
        const float* xr0 = x + ((size_t)bat0 * 64 + R + l15) * 256;
        const float* xr1 = x + ((size_t)bat1 * 64 + R + l15) * 256;
        #pragma unroll
        for (int t = 0; t < 8; ++t) {
            xa0[t] = cvt8(xr0 + t * 32 + quad * 8);
            xa1[t] = cvt8(xr1 + t * 32 + quad * 8);
        }
    }

    bf16x8 oa0[8], oa1[8];   // out A-frags (layer-2/3 input)
    bf16x8 qa0[8], qa1[8];   // q  A-frags (logits input)

    // ---------------- layer 1: out = relu(x@w1.T + b1) -> oa ----------------
    {
        const bf16_t* wl = wf;
        #pragma unroll
        for (int n = 0; n < 16; ++n) {
            float bias = b1[n * 16 + l15];
            f32x4 s0, s1;
            gemm2<USE_WS>(xa0, xa1, wl, w1, n, lane, s0, s1);
            #pragma unroll
            for (int r2 = 0; r2 < 4; ++r2) {
                int off = ks_off(R + quad * 4 + r2, n * 16 + l15);
                *(bf16_t*)(u_lds + off)         = (bf16_t)fmaxf(s0[r2] + bias, 0.f);
                *(bf16_t*)(u_lds + 32768 + off) = (bf16_t)fmaxf(s1[r2] + bias, 0.f);
            }
        }
        #pragma unroll
        for (int t = 0; t < 8; ++t) {
            int off = ks_off(R + l15, t * 32 + quad * 8);
            oa0[t] = *(const bf16x8*)(u_lds + off);
            oa1[t] = *(const bf16x8*)(u_lds + 32768 + off);
        }
    }

    // ---------------- layer 2: q = out@w2.T + b2 -> qa ----------------
    {
        const bf16_t* wl = wf + 65536;
        #pragma unroll
        for (int n = 0; n < 16; ++n) {
            float bias = b2[n * 16 + l15];
            f32x4 s0, s1;
            gemm2<USE_WS>(oa0, oa1, wl, w2, n, lane, s0, s1);
            #pragma unroll
            for (int r2 = 0; r2 < 4; ++r2) {
                int off = ks_off(R + quad * 4 + r2, n * 16 + l15);
                *(bf16_t*)(u_lds + off)         = (bf16_t)(s0[r2] + bias);
                *(bf16_t*)(u_lds + 32768 + off) = (bf16_t)(s1[r2] + bias);
            }
        }
        #pragma unroll
        for (int t = 0; t < 8; ++t) {
            int off = ks_off(R + l15, t * 32 + quad * 8);
            qa0[t] = *(const bf16x8*)(u_lds + off);
            qa1[t] = *(const bf16x8*)(u_lds + 32768 + off);
        }
    }

    // ---------------- layer 3: k = out@w3.T + b3 -> ks (LDS) ----------------
    {
        const bf16_t* wl = wf + 2 * 65536;
        #pragma unroll
        for (int n = 0; n < 16; ++n) {
            float bias = b3[n * 16 + l15];
            f32x4 s0, s1;
            gemm2<USE_WS>(oa0, oa1, wl, w3, n, lane, s0, s1);
            #pragma unroll
            for (int r2 = 0; r2 < 4; ++r2) {
                int off = ks_off(R + quad * 4 + r2, n * 16 + l15);
                *(bf16_t*)(u_lds + off)         = (bf16_t)(s0[r2] + bias);
                *(bf16_t*)(u_lds + 32768 + off) = (bf16_t)(s1[r2] + bias);
            }
        }
    }

    __syncthreads();   // #1: both k-buffers complete across all waves

    // ---------------- logits = q@k.T * SCALE -> registers -------------------
    f32x4 la0[4], la1[4];
    {
        #pragma unroll
        for (int n = 0; n < 4; ++n) {
            f32x4 a00 = {0.f,0.f,0.f,0.f}, a01 = {0.f,0.f,0.f,0.f};
            f32x4 a10 = {0.f,0.f,0.f,0.f}, a11 = {0.f,0.f,0.f,0.f};
            #pragma unroll
            for (int t = 0; t < 8; t += 2) {
                int o0 = ks_off(n * 16 + l15, t * 32 + quad * 8);
                int o1 = ks_off(n * 16 + l15, (t + 1) * 32 + quad * 8);
                bf16x8 k00 = *(const bf16x8*)(u_lds + o0);
                bf16x8 k01 = *(const bf16x8*)(u_lds + o1);
                bf16x8 k10 = *(const bf16x8*)(u_lds + 32768 + o0);
                bf16x8 k11 = *(const bf16x8*)(u_lds + 32768 + o1);
                a00 = __builtin_amdgcn_mfma_f32_16x16x32_bf16(qa0[t],     k00, a00, 0, 0, 0);
                a10 = __builtin_amdgcn_mfma_f32_16x16x32_bf16(qa1[t],     k10, a10, 0, 0, 0);
                a01 = __builtin_amdgcn_mfma_f32_16x16x32_bf16(qa0[t + 1], k01, a01, 0, 0, 0);
                a11 = __builtin_amdgcn_mfma_f32_16x16x32_bf16(qa1[t + 1], k11, a11, 0, 0, 0);
            }
            la0[n] = a00 + a01;
            la1[n] = a10 + a11;
        }
    }

    // ---------------- promo offsets: offs[p][s] = k[56+s]·w4[p] -------------
    {
        int s = lane >> 3, seg = lane & 7;     // wave wv handles p = wv
        const float* wrow = w4 + wv * 256;
        #pragma unroll
        for (int b = 0; b < 2; ++b) {
            const unsigned char* kb = u_lds + b * 32768;
            float p = 0.f;
            #pragma unroll
            for (int m = 0; m < 4; ++m) {
                bf16x8 kv = *(const bf16x8*)(kb + ks_off(56 + s, seg * 32 + m * 8));
                f32x4 wa = *(const f32x4*)(wrow + seg * 32 + m * 8);
                f32x4 wb = *(const f32x4*)(wrow + seg * 32 + m * 8 + 4);
                p += (float)kv[0] * wa[0] + (float)kv[1] * wa[1]
                   + (float)kv[2] * wa[2] + (float)kv[3] * wa[3]
                   + (float)kv[4] * wb[0] + (float)kv[5] * wb[1]
                   + (float)kv[6] * wb[2] + (float)kv[7] * wb[3];
            }
            p += __shfl_down(p, 4);
            p += __shfl_down(p, 2);
            p += __shfl_down(p, 1);
            if (seg == 0) promoLDS[b][wv][s] = p;
        }
    }

    // wave 3 stages the logits[48:56, 56:64] patch (rows 48-55 = quads 0,1)
    if (wv == 3 && quad < 2 && l15 >= 8) {
        #pragma unroll
        for (int r2 = 0; r2 < 4; ++r2) {
            patchLDS[0][quad * 4 + r2][l15 - 8] = la0[3][r2] * PSCALE;
            patchLDS[1][quad * 4 + r2][l15 - 8] = la1[3][r2] * PSCALE;
        }
    }

    __syncthreads();   // #2: everyone done READING k; promoLDS/patch ready

    // ---------------- fullbuf (aliased over k regions) ----------------------
    float* fb0 = (float*)u_lds;
    float* fb1 = (float*)(u_lds + 32768);
    #pragma unroll
    for (int n = 0; n < 4; ++n) {
        #pragma unroll
        for (int r2 = 0; r2 < 4; ++r2) {
            int idx = (R + quad * 4 + r2) * 64 + n * 16 + l15;
            fb0[idx] = la0[n][r2] * PSCALE;
            fb1[idx] = la1[n][r2] * PSCALE;
        }
    }

    // promo rows 64..66 (reads patchLDS/promoLDS only)
    if (tid < 192) {
        int u = tid >> 6, vv = tid & 63;
        int mm = u * 64 + vv;                  // flat 0..191 over (8 x 24)
        int r_ = mm / 24, c_ = mm - r_ * 24;
        int c3 = c_ / 3, cp = c_ - c3 * 3;     // c3 = s (0..7), cp = p (0..2)
        fb0[(64 + u) * 64 + vv] =
            promoLDS[0][cp][c3] + promoLDS[0][3][c3] + patchLDS[0][r_][c3];
        fb1[(64 + u) * 64 + vv] =
            promoLDS[1][cp][c3] + promoLDS[1][3][c3] + patchLDS[1][r_][c3];
    }

    __syncthreads();   // #3: fullbufs ready

    // ---------------- gather (shared gidx loads, both batches) --------------
    {
        float* orow0 = out + (size_t)bat0 * NPOL;
        float* orow1 = out + (size_t)(bat0 + 1) * NPOL;
        int   idxv[8];
        float v0[8], v1[8];
        #pragma unroll
        for (int i = 0; i < 8; ++i) {
            int g = tid + i * 256;
            idxv[i] = (g < NPOL) ? gidx[g] : 0;
        }
        #pragma unroll
        for (int i = 0; i < 8; ++i) {
            v0[i] = fb0[idxv[i]];
            v1[i] = fb1[idxv[i]];
        }
        #pragma unroll
        for (int i = 0; i < 8; ++i) {
            int g = tid + i * 256;
            if (g < NPOL) {
                orow0[g] = v0[i];
                if (has1) orow1[g] = v1[i];
            }
        }
    }
}

extern "C" void kernel_launch(void* const* d_in, const int* in_sizes, int n_in,
                              void* d_out, int out_size, void* d_ws, size_t ws_size,
                              hipStream_t stream) {
    const float* x    = (const float*)d_in[0];
    const float* w1   = (const float*)d_in[1];
    const float* b1   = (const float*)d_in[2];
    const float* w2   = (const float*)d_in[3];
    const float* b2   = (const float*)d_in[4];
    const float* w3   = (const float*)d_in[5];
    const float* b3   = (const float*)d_in[6];
    const float* w4   = (const float*)d_in[7];
    const int*   gidx = (const int*)d_in[8];
    float* out = (float*)d_out;
    bf16_t* wf = (bf16_t*)d_ws;                 // needs 3*65536 bf16 = 384 KB

    int nbat = in_sizes[0] / (64 * 256);        // 4096
    int nblk = (nbat + 1) / 2;
    const size_t ws_needed = (size_t)3 * 65536 * sizeof(bf16_t);

    if (ws_size >= ws_needed) {
        prep_weights<<<768, 256, 0, stream>>>(w1, w2, w3, wf);
        policy_main<true><<<nblk, 256, 0, stream>>>(
            x, wf, w1, w2, w3, b1, b2, b3, w4, gidx, out, nbat);
    } else {
        policy_main<false><<<nblk, 256, 0, stream>>>(
            x, wf, w1, w2, w3, b1, b2, b3, w4, gidx, out, nbat);
    }
}

// Round 4
// 512.498 us; speedup vs baseline: 2.1772x; 1.1502x over previous
//
#include <hip/hip_runtime.h>

// PolicyHead fused kernel, R6.
// R5 post-mortem: 321us, MfmaUtil 14% == total-MFMA-work/walltime -> pure
// latency-bound. Neither HBM (7%) nor per-XCD L2 BW (~1.2 of 4.3 TB/s) is
// saturated. LDS (66.5KB) caps occupancy at 2 blocks/CU, so VGPR budget is
// 256/wave but compiler used only 128 -> few weight loads in flight; each
// n-tile's MFMA chain eats a full L2 latency.
// R6: explicit 1-ahead software pipeline for weight fragments in all three
// layers: double-buffer wb0/wb1[8] (64 VGPRs), issue n+1's 8 loads before
// n's 16 MFMAs. Statically unrolled pair-loop (no runtime-indexed local
// arrays -> no scratch). Everything else identical to R5.

typedef __bf16 bf16_t;
typedef __bf16 bf16x8 __attribute__((ext_vector_type(8)));
typedef float  f32x4  __attribute__((ext_vector_type(4)));

#define PSCALE 0.0625f
#define NPOL   1858

__global__ void prep_weights(const float* __restrict__ w1,
                             const float* __restrict__ w2,
                             const float* __restrict__ w3,
                             bf16_t* __restrict__ wf) {
    // wf flat layout: [which][n(16)][t(8)][lane(64)][j(8)]
    int i = blockIdx.x * 256 + threadIdx.x;      // 0 .. 3*65536-1
    int which = i >> 16;
    int r = i & 65535;
    int j    = r & 7;
    int lane = (r >> 3) & 63;
    int t    = (r >> 9) & 7;
    int n    = (r >> 12) & 15;
    const float* w = (which == 0) ? w1 : (which == 1 ? w2 : w3);
    int row = n * 16 + (lane & 15);              // output-col index (w row)
    int col = t * 32 + (lane >> 4) * 8 + j;      // k index
    wf[i] = (bf16_t)w[row * 256 + col];
}

// B-operand fragment for col-tile n, k-tile t: lane holds
// w[n*16 + (lane&15)][t*32 + (lane>>4)*8 + j], j=0..7.
template <bool USE_WS>
__device__ __forceinline__ bf16x8 wfrag(const bf16_t* __restrict__ wl,
                                        const float* __restrict__ w,
                                        int n, int t, int lane) {
    if (USE_WS) {
        return *(const bf16x8*)(wl + (((n * 8 + t) * 64 + lane) << 3));
    } else {
        int l15 = lane & 15, quad = lane >> 4;
        const float* p = w + (n * 16 + l15) * 256 + t * 32 + quad * 8;
        f32x4 lo = *(const f32x4*)p;
        f32x4 hi = *(const f32x4*)(p + 4);
        bf16x8 v;
        v[0] = (bf16_t)lo[0]; v[1] = (bf16_t)lo[1];
        v[2] = (bf16_t)lo[2]; v[3] = (bf16_t)lo[3];
        v[4] = (bf16_t)hi[0]; v[5] = (bf16_t)hi[1];
        v[6] = (bf16_t)hi[2]; v[7] = (bf16_t)hi[3];
        return v;
    }
}

// Swizzled byte offset into a 64x256 bf16 buffer (32768 B).
// b128 reads at col%8==0 stay 16B-aligned (XOR touches bits 4..6 only).
__device__ __forceinline__ int ks_off(int row, int col) {
    return ((row << 9) + (col << 1)) ^ ((row & 7) << 4);
}

__device__ __forceinline__ bf16x8 cvt8(const float* __restrict__ p) {
    f32x4 lo = *(const f32x4*)p;
    f32x4 hi = *(const f32x4*)(p + 4);
    bf16x8 v;
    v[0] = (bf16_t)lo[0]; v[1] = (bf16_t)lo[1];
    v[2] = (bf16_t)lo[2]; v[3] = (bf16_t)lo[3];
    v[4] = (bf16_t)hi[0]; v[5] = (bf16_t)hi[1];
    v[6] = (bf16_t)hi[2]; v[7] = (bf16_t)hi[3];
    return v;
}

// 16 MFMAs (2 batches x 8 k-tiles) against one weight-fragment set, 4 chains.
__device__ __forceinline__ void mfma16(const bf16x8* inA, const bf16x8* inB,
                                       const bf16x8* w, f32x4& s0, f32x4& s1) {
    f32x4 a00 = {0.f,0.f,0.f,0.f}, a01 = {0.f,0.f,0.f,0.f};
    f32x4 a10 = {0.f,0.f,0.f,0.f}, a11 = {0.f,0.f,0.f,0.f};
    #pragma unroll
    for (int t = 0; t < 8; t += 2) {
        a00 = __builtin_amdgcn_mfma_f32_16x16x32_bf16(inA[t],     w[t],     a00, 0, 0, 0);
        a10 = __builtin_amdgcn_mfma_f32_16x16x32_bf16(inB[t],     w[t],     a10, 0, 0, 0);
        a01 = __builtin_amdgcn_mfma_f32_16x16x32_bf16(inA[t + 1], w[t + 1], a01, 0, 0, 0);
        a11 = __builtin_amdgcn_mfma_f32_16x16x32_bf16(inB[t + 1], w[t + 1], a11, 0, 0, 0);
    }
    s0 = a00 + a01;
    s1 = a10 + a11;
}

// One full 256->256 layer for both batches, 1-ahead pipelined weight loads.
template <bool USE_WS, bool RELU>
__device__ __forceinline__ void layer_pass(const bf16x8* inA, const bf16x8* inB,
                                           const bf16_t* __restrict__ wl,
                                           const float* __restrict__ wraw,
                                           const float* __restrict__ bias,
                                           unsigned char* __restrict__ u_lds,
                                           int lane, int quad, int l15, int R) {
    bf16x8 wb0[8], wb1[8];
    #pragma unroll
    for (int t = 0; t < 8; ++t)
        wb0[t] = wfrag<USE_WS>(wl, wraw, 0, t, lane);

    #pragma unroll
    for (int np = 0; np < 8; ++np) {
        const int nE = 2 * np, nO = nE + 1;

        // issue odd-tile loads; compute even tile under them
        #pragma unroll
        for (int t = 0; t < 8; ++t)
            wb1[t] = wfrag<USE_WS>(wl, wraw, nO, t, lane);
        {
            f32x4 s0, s1;
            mfma16(inA, inB, wb0, s0, s1);
            float bv = bias[nE * 16 + l15];
            #pragma unroll
            for (int r2 = 0; r2 < 4; ++r2) {
                int off = ks_off(R + quad * 4 + r2, nE * 16 + l15);
                float v0 = s0[r2] + bv, v1 = s1[r2] + bv;
                if (RELU) { v0 = fmaxf(v0, 0.f); v1 = fmaxf(v1, 0.f); }
                *(bf16_t*)(u_lds + off)         = (bf16_t)v0;
                *(bf16_t*)(u_lds + 32768 + off) = (bf16_t)v1;
            }
        }

        // issue next even-tile loads; compute odd tile under them
        if (np < 7) {
            #pragma unroll
            for (int t = 0; t < 8; ++t)
                wb0[t] = wfrag<USE_WS>(wl, wraw, nE + 2, t, lane);
        }
        {
            f32x4 s0, s1;
            mfma16(inA, inB, wb1, s0, s1);
            float bv = bias[nO * 16 + l15];
            #pragma unroll
            for (int r2 = 0; r2 < 4; ++r2) {
                int off = ks_off(R + quad * 4 + r2, nO * 16 + l15);
                float v0 = s0[r2] + bv, v1 = s1[r2] + bv;
                if (RELU) { v0 = fmaxf(v0, 0.f); v1 = fmaxf(v1, 0.f); }
                *(bf16_t*)(u_lds + off)         = (bf16_t)v0;
                *(bf16_t*)(u_lds + 32768 + off) = (bf16_t)v1;
            }
        }
    }
}

template <bool USE_WS>
__global__ __launch_bounds__(256, 2)
void policy_main(const float* __restrict__ x,
                 const bf16_t* __restrict__ wf,   // [3][16][8][64][8] bf16
                 const float* __restrict__ w1,
                 const float* __restrict__ w2,
                 const float* __restrict__ w3,
                 const float* __restrict__ b1,
                 const float* __restrict__ b2,
                 const float* __restrict__ b3,
                 const float* __restrict__ w4,
                 const int*   __restrict__ gidx,
                 float* __restrict__ out,
                 int nbat) {
    // Two 32768 B unions: phase A = k (64x256 bf16, XOR-swizzled) per batch;
    //                     phase B = fullbuf (67x64 f32 = 17152 B) per batch.
    __shared__ __align__(16) unsigned char u_lds[2 * 32768];
    __shared__ float promoLDS[2][4][8];
    __shared__ float patchLDS[2][8][8];  // logits[48:56, 56:64], scaled

    const int tid  = threadIdx.x;
    const int lane = tid & 63;
    const int wv   = tid >> 6;        // wave id 0..3
    const int quad = lane >> 4;       // 0..3
    const int l15  = lane & 15;
    const int R    = wv * 16;         // row base within batch

    const int bat0 = blockIdx.x * 2;
    const bool has1 = (bat0 + 1) < nbat;
    const int bat1 = has1 ? bat0 + 1 : bat0;   // clamp: compute dup, skip store

    // ---- x A-fragments (fp32 -> bf16), both batches ----
    bf16x8 xa0[8], xa1[8];
    {
        const float* xr0 = x + ((size_t)bat0 * 64 + R + l15) * 256;
        const float* xr1 = x + ((size_t)bat1 * 64 + R + l15) * 256;
        #pragma unroll
        for (int t = 0; t < 8; ++t) {
            xa0[t] = cvt8(xr0 + t * 32 + quad * 8);
            xa1[t] = cvt8(xr1 + t * 32 + quad * 8);
        }
    }

    bf16x8 oa0[8], oa1[8];   // out A-frags (layer-2/3 input)
    bf16x8 qa0[8], qa1[8];   // q  A-frags (logits input)

    // ---------------- layer 1: out = relu(x@w1.T + b1) ----------------
    layer_pass<USE_WS, true>(xa0, xa1, wf, w1, b1, u_lds, lane, quad, l15, R);
    #pragma unroll
    for (int t = 0; t < 8; ++t) {
        int off = ks_off(R + l15, t * 32 + quad * 8);
        oa0[t] = *(const bf16x8*)(u_lds + off);
        oa1[t] = *(const bf16x8*)(u_lds + 32768 + off);
    }

    // ---------------- layer 2: q = out@w2.T + b2 ----------------
    layer_pass<USE_WS, false>(oa0, oa1, wf + 65536, w2, b2, u_lds, lane, quad, l15, R);
    #pragma unroll
    for (int t = 0; t < 8; ++t) {
        int off = ks_off(R + l15, t * 32 + quad * 8);
        qa0[t] = *(const bf16x8*)(u_lds + off);
        qa1[t] = *(const bf16x8*)(u_lds + 32768 + off);
    }

    // ---------------- layer 3: k = out@w3.T + b3 -> ks (LDS) ----------------
    layer_pass<USE_WS, false>(oa0, oa1, wf + 2 * 65536, w3, b3, u_lds, lane, quad, l15, R);

    __syncthreads();   // #1: both k-buffers complete across all waves

    // ---------------- logits = q@k.T * SCALE -> registers -------------------
    f32x4 la0[4], la1[4];
    {
        #pragma unroll
        for (int n = 0; n < 4; ++n) {
            f32x4 a00 = {0.f,0.f,0.f,0.f}, a01 = {0.f,0.f,0.f,0.f};
            f32x4 a10 = {0.f,0.f,0.f,0.f}, a11 = {0.f,0.f,0.f,0.f};
            #pragma unroll
            for (int t = 0; t < 8; t += 2) {
                int o0 = ks_off(n * 16 + l15, t * 32 + quad * 8);
                int o1 = ks_off(n * 16 + l15, (t + 1) * 32 + quad * 8);
                bf16x8 k00 = *(const bf16x8*)(u_lds + o0);
                bf16x8 k01 = *(const bf16x8*)(u_lds + o1);
                bf16x8 k10 = *(const bf16x8*)(u_lds + 32768 + o0);
                bf16x8 k11 = *(const bf16x8*)(u_lds + 32768 + o1);
                a00 = __builtin_amdgcn_mfma_f32_16x16x32_bf16(qa0[t],     k00, a00, 0, 0, 0);
                a10 = __builtin_amdgcn_mfma_f32_16x16x32_bf16(qa1[t],     k10, a10, 0, 0, 0);
                a01 = __builtin_amdgcn_mfma_f32_16x16x32_bf16(qa0[t + 1], k01, a01, 0, 0, 0);
                a11 = __builtin_amdgcn_mfma_f32_16x16x32_bf16(qa1[t + 1], k11, a11, 0, 0, 0);
            }
            la0[n] = a00 + a01;
            la1[n] = a10 + a11;
        }
    }

    // ---------------- promo offsets: offs[p][s] = k[56+s]·w4[p] -------------
    {
        int s = lane >> 3, seg = lane & 7;     // wave wv handles p = wv
        const float* wrow = w4 + wv * 256;
        #pragma unroll
        for (int b = 0; b < 2; ++b) {
            const unsigned char* kb = u_lds + b * 32768;
            float p = 0.f;
            #pragma unroll
            for (int m = 0; m < 4; ++m) {
                bf16x8 kv = *(const bf16x8*)(kb + ks_off(56 + s, seg * 32 + m * 8));
                f32x4 wa = *(const f32x4*)(wrow + seg * 32 + m * 8);
                f32x4 wb = *(const f32x4*)(wrow + seg * 32 + m * 8 + 4);
                p += (float)kv[0] * wa[0] + (float)kv[1] * wa[1]
                   + (float)kv[2] * wa[2] + (float)kv[3] * wa[3]
                   + (float)kv[4] * wb[0] + (float)kv[5] * wb[1]
                   + (float)kv[6] * wb[2] + (float)kv[7] * wb[3];
            }
            p += __shfl_down(p, 4);
            p += __shfl_down(p, 2);
            p += __shfl_down(p, 1);
            if (seg == 0) promoLDS[b][wv][s] = p;
        }
    }

    // wave 3 stages the logits[48:56, 56:64] patch (rows 48-55 = quads 0,1)
    if (wv == 3 && quad < 2 && l15 >= 8) {
        #pragma unroll
        for (int r2 = 0; r2 < 4; ++r2) {
            patchLDS[0][quad * 4 + r2][l15 - 8] = la0[3][r2] * PSCALE;
            patchLDS[1][quad * 4 + r2][l15 - 8] = la1[3][r2] * PSCALE;
        }
    }

    __syncthreads();   // #2: everyone done READING k; promoLDS/patch ready

    // ---------------- fullbuf (aliased over k regions) ----------------------
    float* fb0 = (float*)u_lds;
    float* fb1 = (float*)(u_lds + 32768);
    #pragma unroll
    for (int n = 0; n < 4; ++n) {
        #pragma unroll
        for (int r2 = 0; r2 < 4; ++r2) {
            int idx = (R + quad * 4 + r2) * 64 + n * 16 + l15;
            fb0[idx] = la0[n][r2] * PSCALE;
            fb1[idx] = la1[n][r2] * PSCALE;
        }
    }

    // promo rows 64..66 (reads patchLDS/promoLDS only)
    if (tid < 192) {
        int u = tid >> 6, vv = tid & 63;
        int mm = u * 64 + vv;                  // flat 0..191 over (8 x 24)
        int r_ = mm / 24, c_ = mm - r_ * 24;
        int c3 = c_ / 3, cp = c_ - c3 * 3;     // c3 = s (0..7), cp = p (0..2)
        fb0[(64 + u) * 64 + vv] =
            promoLDS[0][cp][c3] + promoLDS[0][3][c3] + patchLDS[0][r_][c3];
        fb1[(64 + u) * 64 + vv] =
            promoLDS[1][cp][c3] + promoLDS[1][3][c3] + patchLDS[1][r_][c3];
    }

    __syncthreads();   // #3: fullbufs ready

    // ---------------- gather (shared gidx loads, both batches) --------------
    {
        float* orow0 = out + (size_t)bat0 * NPOL;
        float* orow1 = out + (size_t)(bat0 + 1) * NPOL;
        int   idxv[8];
        float v0[8], v1[8];
        #pragma unroll
        for (int i = 0; i < 8; ++i) {
            int g = tid + i * 256;
            idxv[i] = (g < NPOL) ? gidx[g] : 0;
        }
        #pragma unroll
        for (int i = 0; i < 8; ++i) {
            v0[i] = fb0[idxv[i]];
            v1[i] = fb1[idxv[i]];
        }
        #pragma unroll
        for (int i = 0; i < 8; ++i) {
            int g = tid + i * 256;
            if (g < NPOL) {
                orow0[g] = v0[i];
                if (has1) orow1[g] = v1[i];
            }
        }
    }
}

extern "C" void kernel_launch(void* const* d_in, const int* in_sizes, int n_in,
                              void* d_out, int out_size, void* d_ws, size_t ws_size,
                              hipStream_t stream) {
    const float* x    = (const float*)d_in[0];
    const float* w1   = (const float*)d_in[1];
    const float* b1   = (const float*)d_in[2];
    const float* w2   = (const float*)d_in[3];
    const float* b2   = (const float*)d_in[4];
    const float* w3   = (const float*)d_in[5];
    const float* b3   = (const float*)d_in[6];
    const float* w4   = (const float*)d_in[7];
    const int*   gidx = (const int*)d_in[8];
    float* out = (float*)d_out;
    bf16_t* wf = (bf16_t*)d_ws;                 // needs 3*65536 bf16 = 384 KB

    int nbat = in_sizes[0] / (64 * 256);        // 4096
    int nblk = (nbat + 1) / 2;
    const size_t ws_needed = (size_t)3 * 65536 * sizeof(bf16_t);

    if (ws_size >= ws_needed) {
        prep_weights<<<768, 256, 0, stream>>>(w1, w2, w3, wf);
        policy_main<true><<<nblk, 256, 0, stream>>>(
            x, wf, w1, w2, w3, b1, b2, b3, w4, gidx, out, nbat);
    } else {
        policy_main<false><<<nblk, 256, 0, stream>>>(
            x, wf, w1, w2, w3, b1, b2, b3, w4, gidx, out, nbat);
    }
}